// Round 2
// baseline (1105.186 us; speedup 1.0000x reference)
//
#include <hip/hip_runtime.h>
#include <math.h>

#define NN 100000      // nodes
#define NE 1600000     // edges
#define NG 512         // graphs
#define LN_EPS 1e-5f

typedef __attribute__((ext_vector_type(8))) short short8;
typedef __attribute__((ext_vector_type(8))) unsigned short ushort8;
typedef __attribute__((ext_vector_type(4))) float floatx4;

union BF8 { short8 v; short s[8]; };
union U8  { ushort8 v; unsigned short s[8]; };
union F4  { floatx4 v; float f[4]; };

static __device__ __forceinline__ short f2bf(float f) {
    union { float f; unsigned u; } a; a.f = f;
    unsigned u = a.u;
    unsigned r = (u + 0x7fffu + ((u >> 16) & 1u)) >> 16;   // RNE
    return (short)r;
}
static __device__ __forceinline__ float bf2f(unsigned short h) {
    union { unsigned u; float f; } a; a.u = ((unsigned)h) << 16;
    return a.f;
}
static __device__ __forceinline__ float silu_f(float v) {
    return v / (1.0f + __expf(-v));
}

// ===========================================================================
// Counting sort of edges by dst (gives the scatter-add L2 locality).
// ===========================================================================
__global__ __launch_bounds__(256)
void hist_kernel(const int* __restrict__ dst, int* __restrict__ cnt)
{
    for (int e = blockIdx.x * blockDim.x + threadIdx.x; e < NE;
         e += gridDim.x * blockDim.x)
        atomicAdd(&cnt[dst[e]], 1);
}

#define SCAN_CHUNK 1024
#define SCAN_NB ((NN + SCAN_CHUNK - 1) / SCAN_CHUNK)   // 98

__global__ __launch_bounds__(256)
void scan_partial_kernel(const int* __restrict__ cnt, int* __restrict__ bsums)
{
    __shared__ int sdata[256];
    const int b = blockIdx.x, t = threadIdx.x;
    const int base = b * SCAN_CHUNK + t * 4;
    int s = 0;
    #pragma unroll
    for (int i = 0; i < 4; ++i) {
        const int idx = base + i;
        s += (idx < NN) ? cnt[idx] : 0;
    }
    sdata[t] = s;
    __syncthreads();
    for (int off = 128; off > 0; off >>= 1) {
        if (t < off) sdata[t] += sdata[t + off];
        __syncthreads();
    }
    if (t == 0) bsums[b] = sdata[0];
}

__global__ void scan_top_kernel(int* __restrict__ bsums)
{
    if (threadIdx.x == 0 && blockIdx.x == 0) {
        int run = 0;
        for (int i = 0; i < SCAN_NB; ++i) { const int v = bsums[i]; bsums[i] = run; run += v; }
    }
}

__global__ __launch_bounds__(256)
void scan_final_kernel(int* __restrict__ cnt, const int* __restrict__ bsums)
{
    __shared__ int sdata[256];
    const int b = blockIdx.x, t = threadIdx.x;
    const int base = b * SCAN_CHUNK + t * 4;
    int c[4];
    #pragma unroll
    for (int i = 0; i < 4; ++i) {
        const int idx = base + i;
        c[i] = (idx < NN) ? cnt[idx] : 0;
    }
    const int tsum = c[0] + c[1] + c[2] + c[3];
    sdata[t] = tsum;
    __syncthreads();
    // inclusive scan (Hillis-Steele)
    for (int off = 1; off < 256; off <<= 1) {
        const int v = (t >= off) ? sdata[t - off] : 0;
        __syncthreads();
        sdata[t] += v;
        __syncthreads();
    }
    int off0 = bsums[b] + sdata[t] - tsum;   // exclusive within chunk + chunk base
    #pragma unroll
    for (int i = 0; i < 4; ++i) {
        const int idx = base + i;
        if (idx < NN) cnt[idx] = off0;
        off0 += c[i];
    }
}

__global__ __launch_bounds__(256)
void scatter_kernel(const int* __restrict__ dst, int* __restrict__ starts,
                    int* __restrict__ perm)
{
    for (int e = blockIdx.x * blockDim.x + threadIdx.x; e < NE;
         e += gridDim.x * blockDim.x) {
        const int pos = atomicAdd(&starts[dst[e]], 1);
        perm[pos] = e;
    }
}

// ===========================================================================
// Edge kernel: per wave, one 16-edge x 64-col tile (edges taken via perm, so
// dst is ascending -> scatter atomics hit an L2-resident sliding window).
//   EA  = silu(edge_attr @ We + be)          (MFMA 1)
//   T   = relu(x[src] + EA)                  (LDS C->A layout round-trip)
//   msg = silu(T @ Wm + bm)                  (MFMA 2)
//   chain-combined atomicAdd into agg[dst]
// mfma_f32_16x16x32_bf16 layouts (HW-verified):
//   A: m = lane&15, k = (lane>>4)*8 + j ; C/D: col = lane&15, row = q*4 + r
// ===========================================================================
__global__ __launch_bounds__(256)
void edge_kernel(const float* __restrict__ x,
                 const int* __restrict__ src,
                 const int* __restrict__ dst,
                 const float* __restrict__ eattr,
                 const int* __restrict__ perm,   // may be null (fallback)
                 const float* __restrict__ We,
                 const float* __restrict__ be,
                 const float* __restrict__ Wm,
                 const float* __restrict__ bm,
                 float* __restrict__ agg)
{
    __shared__ unsigned short lds[4][16 * 72];
    const int lane = threadIdx.x & 63;
    const int wid  = threadIdx.x >> 6;
    const int m = lane & 15;
    const int q = lane >> 4;
    unsigned short* tile = lds[wid];

    short8 wef[2][4], wmf[2][4];
    float bev[4], bmv[4];
    #pragma unroll
    for (int kh = 0; kh < 2; ++kh) {
        #pragma unroll
        for (int t = 0; t < 4; ++t) {
            BF8 fe, fm;
            #pragma unroll
            for (int j = 0; j < 8; ++j) {
                const int k = kh * 32 + q * 8 + j;
                const int n = m + 16 * t;
                fe.s[j] = f2bf(We[k * 64 + n]);
                fm.s[j] = f2bf(Wm[k * 64 + n]);
            }
            wef[kh][t] = fe.v; wmf[kh][t] = fm.v;
        }
    }
    #pragma unroll
    for (int t = 0; t < 4; ++t) { bev[t] = be[m + 16 * t]; bmv[t] = bm[m + 16 * t]; }

    const int n_tiles = NE / 16;
    const int stride  = gridDim.x * 4;
    for (int tl = blockIdx.x * 4 + wid; tl < n_tiles; tl += stride) {
        const int e0 = tl * 16;
        const int em = perm ? perm[e0 + m] : (e0 + m);   // this lane's A-row edge

        // ---- matmul 1: A = edge_attr[em] ----
        short8 a1[2];
        #pragma unroll
        for (int kh = 0; kh < 2; ++kh) {
            const float* p = eattr + (size_t)em * 64 + kh * 32 + q * 8;
            F4 v0, v1; v0.v = *(const floatx4*)p; v1.v = *(const floatx4*)(p + 4);
            BF8 f;
            #pragma unroll
            for (int j = 0; j < 4; ++j) { f.s[j] = f2bf(v0.f[j]); f.s[j + 4] = f2bf(v1.f[j]); }
            a1[kh] = f.v;
        }
        floatx4 acc[4];
        #pragma unroll
        for (int t = 0; t < 4; ++t) acc[t] = (floatx4){0.f, 0.f, 0.f, 0.f};
        #pragma unroll
        for (int kh = 0; kh < 2; ++kh)
            #pragma unroll
            for (int t = 0; t < 4; ++t)
                acc[t] = __builtin_amdgcn_mfma_f32_16x16x32_bf16(a1[kh], wef[kh][t], acc[t], 0, 0, 0);

        #pragma unroll
        for (int t = 0; t < 4; ++t)
            #pragma unroll
            for (int r = 0; r < 4; ++r) {
                const float v = silu_f(acc[t][r] + bev[t]);
                tile[(q * 4 + r) * 72 + m + 16 * t] = (unsigned short)f2bf(v);
            }
        __asm__ volatile("s_waitcnt lgkmcnt(0)" ::: "memory");  // wave-synchronous RAW

        // ---- matmul 2: A = relu(x[src[em]] + EA) ----
        const int sn = src[em];
        short8 a2[2];
        #pragma unroll
        for (int kh = 0; kh < 2; ++kh) {
            U8 t8; t8.v = *(const ushort8*)&tile[m * 72 + kh * 32 + q * 8];
            const float* xp = x + (size_t)sn * 64 + kh * 32 + q * 8;
            F4 x0, x1; x0.v = *(const floatx4*)xp; x1.v = *(const floatx4*)(xp + 4);
            BF8 f;
            #pragma unroll
            for (int j = 0; j < 4; ++j) {
                f.s[j]     = f2bf(fmaxf(bf2f(t8.s[j])     + x0.f[j], 0.0f));
                f.s[j + 4] = f2bf(fmaxf(bf2f(t8.s[j + 4]) + x1.f[j], 0.0f));
            }
            a2[kh] = f.v;
        }
        #pragma unroll
        for (int t = 0; t < 4; ++t) acc[t] = (floatx4){0.f, 0.f, 0.f, 0.f};
        #pragma unroll
        for (int kh = 0; kh < 2; ++kh)
            #pragma unroll
            for (int t = 0; t < 4; ++t)
                acc[t] = __builtin_amdgcn_mfma_f32_16x16x32_bf16(a2[kh], wmf[kh][t], acc[t], 0, 0, 0);

        // dst nodes for the 4 C-rows this lane owns (rows q*4+r). Row i's edge id
        // is held by lane i (i<16), so broadcast via shuffle.
        int dn[4];
        #pragma unroll
        for (int r = 0; r < 4; ++r) {
            const int er = perm ? __shfl(em, q * 4 + r, 64) : (e0 + q * 4 + r);
            dn[r] = dst[er];
        }
        // silu + bias, then chain-combine consecutive rows sharing a dst
        float sv[4][4];
        #pragma unroll
        for (int t = 0; t < 4; ++t)
            #pragma unroll
            for (int r = 0; r < 4; ++r)
                sv[t][r] = silu_f(acc[t][r] + bmv[t]);
        #pragma unroll
        for (int t = 0; t < 4; ++t) {
            const int col = m + 16 * t;
            float run = sv[t][0];
            #pragma unroll
            for (int r = 1; r < 4; ++r) {
                if (dn[r] == dn[r - 1]) run += sv[t][r];
                else { atomicAdd(agg + (size_t)dn[r - 1] * 64 + col, run); run = sv[t][r]; }
            }
            atomicAdd(agg + (size_t)dn[3] * 64 + col, run);
        }
    }
}

// ===========================================================================
// Stats: per-graph sum / sumsq / node-count over pre = agg + (1+eps)*x.
// Contiguous per-wave chunk; node2graph is sorted, so accumulate per-lane
// partials across each same-graph run and flush once per run (few atomics).
// ===========================================================================
#define STATS_WAVES 4096
__global__ __launch_bounds__(256)
void stats_kernel(const float* __restrict__ agg,
                  const float* __restrict__ x,
                  const int* __restrict__ n2g,
                  const float* __restrict__ eps,
                  float* __restrict__ gsum,
                  float* __restrict__ gss,
                  float* __restrict__ gcnt)
{
    const int lane = threadIdx.x & 63;
    const int wid  = threadIdx.x >> 6;
    const int w    = blockIdx.x * 4 + wid;
    const int chunk = (NN + STATS_WAVES - 1) / STATS_WAVES;
    const int n0 = w * chunk;
    const int n1 = min(NN, n0 + chunk);
    if (n0 >= n1) return;
    const float k = 1.0f + eps[0];

    int   curg = n2g[n0];
    float s = 0.f, ss = 0.f, rc = 0.f;
    for (int n = n0; n < n1; ++n) {
        const int g = n2g[n];
        if (g != curg) {
            float a = s, b = ss;
            #pragma unroll
            for (int off = 32; off > 0; off >>= 1) {
                a += __shfl_down(a, off, 64);
                b += __shfl_down(b, off, 64);
            }
            if (lane == 0) {
                atomicAdd(&gsum[curg], a);
                atomicAdd(&gss[curg], b);
                atomicAdd(&gcnt[curg], rc);
            }
            s = 0.f; ss = 0.f; rc = 0.f; curg = g;
        }
        const float pre = agg[(size_t)n * 64 + lane] + k * x[(size_t)n * 64 + lane];
        s += pre; ss += pre * pre; rc += (lane == 0) ? 1.0f : 0.0f;
    }
    float a = s, b = ss;
    #pragma unroll
    for (int off = 32; off > 0; off >>= 1) {
        a += __shfl_down(a, off, 64);
        b += __shfl_down(b, off, 64);
    }
    if (lane == 0) {
        atomicAdd(&gsum[curg], a);
        atomicAdd(&gss[curg], b);
        atomicAdd(&gcnt[curg], rc);
    }
}

// ===========================================================================
// Norm + residual + relu, in place over the agg buffer (== d_out).
// ===========================================================================
__global__ __launch_bounds__(256)
void norm_kernel(const float* __restrict__ x,
                 const int* __restrict__ n2g,
                 const float* __restrict__ eps,
                 const float* __restrict__ gamma,
                 const float* __restrict__ beta,
                 const float* __restrict__ gsum,
                 const float* __restrict__ gss,
                 const float* __restrict__ gcnt,
                 float* __restrict__ out)
{
    const float k = 1.0f + eps[0];
    const int total = NN * 16;
    for (int idx = blockIdx.x * blockDim.x + threadIdx.x; idx < total;
         idx += gridDim.x * blockDim.x) {
        const int n  = idx >> 4;
        const int c4 = (idx & 15) * 4;
        const int g  = n2g[n];
        const float cnt  = fmaxf(gcnt[g] * 64.0f, 1.0f);
        const float mean = gsum[g] / cnt;
        const float var  = gss[g] / cnt - mean * mean;
        const float rsig = rsqrtf(var + LN_EPS);
        F4 a, xv, o;
        a.v  = *(const floatx4*)&out[(size_t)n * 64 + c4];
        xv.v = *(const floatx4*)&x[(size_t)n * 64 + c4];
        #pragma unroll
        for (int j = 0; j < 4; ++j) {
            const float pre = a.f[j] + k * xv.f[j];
            const float v = (pre - mean) * rsig * gamma[c4 + j] + beta[c4 + j] + xv.f[j];
            o.f[j] = fmaxf(v, 0.0f);
        }
        *(floatx4*)&out[(size_t)n * 64 + c4] = o.v;
    }
}

extern "C" void kernel_launch(void* const* d_in, const int* in_sizes, int n_in,
                              void* d_out, int out_size, void* d_ws, size_t ws_size,
                              hipStream_t stream)
{
    const float* x      = (const float*)d_in[0];
    const int*   ei     = (const int*)  d_in[1];
    const float* eattr  = (const float*)d_in[2];
    const int*   n2g    = (const int*)  d_in[3];
    // branch-1 params (d_in[4..10]) are dead: conv1's result is overwritten by
    // conv2(x, ...) in the reference. Only branch 2 affects the output.
    const float* We2    = (const float*)d_in[11];
    const float* be2    = (const float*)d_in[12];
    const float* Wm2    = (const float*)d_in[13];
    const float* bm2    = (const float*)d_in[14];
    const float* eps2   = (const float*)d_in[15];
    const float* gamma2 = (const float*)d_in[16];
    const float* beta2  = (const float*)d_in[17];
    const int* src = ei;
    const int* dst = ei + NE;

    float* out  = (float*)d_out;            // doubles as agg scratch
    // ws layout: gsum[512] gss[512] gcnt[512] | bsums[256] | cnt[NN] | perm[NE]
    float* gsum = (float*)d_ws;
    float* gss  = gsum + NG;
    float* gcnt = gss + NG;
    int*   bsums = (int*)(gcnt + NG);
    int*   cnt   = bsums + 256;
    int*   perm  = cnt + NN;
    const size_t ws_need = (size_t)(3 * NG + 256 + NN + NE) * 4;
    const bool do_sort = ws_size >= ws_need;

    hipMemsetAsync(d_out, 0, (size_t)NN * 64 * sizeof(float), stream);
    if (do_sort) {
        // zero gsum/gss/gcnt + cnt (bsums fully overwritten by scan_partial)
        hipMemsetAsync(d_ws, 0, (size_t)(3 * NG + 256 + NN) * 4, stream);
        hist_kernel<<<dim3(512), dim3(256), 0, stream>>>(dst, cnt);
        scan_partial_kernel<<<dim3(SCAN_NB), dim3(256), 0, stream>>>(cnt, bsums);
        scan_top_kernel<<<dim3(1), dim3(64), 0, stream>>>(bsums);
        scan_final_kernel<<<dim3(SCAN_NB), dim3(256), 0, stream>>>(cnt, bsums);
        scatter_kernel<<<dim3(512), dim3(256), 0, stream>>>(dst, cnt, perm);
    } else {
        hipMemsetAsync(d_ws, 0, 3 * NG * sizeof(float), stream);
    }

    edge_kernel<<<dim3(2048), dim3(256), 0, stream>>>(
        x, src, dst, eattr, do_sort ? perm : (const int*)nullptr,
        We2, be2, Wm2, bm2, out);
    stats_kernel<<<dim3(STATS_WAVES / 4), dim3(256), 0, stream>>>(
        out, x, n2g, eps2, gsum, gss, gcnt);
    norm_kernel<<<dim3(1024), dim3(256), 0, stream>>>(
        x, n2g, eps2, gamma2, beta2, gsum, gss, gcnt, out);
}

// Round 3
// 909.640 us; speedup vs baseline: 1.2150x; 1.2150x over previous
//
#include <hip/hip_runtime.h>
#include <math.h>

#define NN 100000      // nodes
#define NE 1600000     // edges
#define NG 512         // graphs
#define LN_EPS 1e-5f

typedef __attribute__((ext_vector_type(8))) short short8;
typedef __attribute__((ext_vector_type(4))) float floatx4;

union BF8 { short8 v; short s[8]; };
union F4  { floatx4 v; float f[4]; };

static __device__ __forceinline__ short f2bf(float f) {
    union { float f; unsigned u; } a; a.f = f;
    unsigned u = a.u;
    unsigned r = (u + 0x7fffu + ((u >> 16) & 1u)) >> 16;   // RNE
    return (short)r;
}
static __device__ __forceinline__ float silu_f(float v) {
    return v / (1.0f + __expf(-v));
}

// ===========================================================================
// Counting sort of edges by dst. Outputs:
//   ps[pos]    = {edge_id, src}  (int2, coalesced reads in edge kernel)
//   dsts_s[pos]= dst             (sorted ascending)
// ===========================================================================
__global__ __launch_bounds__(256)
void hist_kernel(const int* __restrict__ dst, int* __restrict__ cnt)
{
    for (int e = blockIdx.x * blockDim.x + threadIdx.x; e < NE;
         e += gridDim.x * blockDim.x)
        atomicAdd(&cnt[dst[e]], 1);
}

#define SCAN_CHUNK 1024
#define SCAN_NB ((NN + SCAN_CHUNK - 1) / SCAN_CHUNK)   // 98

__global__ __launch_bounds__(256)
void scan_partial_kernel(const int* __restrict__ cnt, int* __restrict__ bsums)
{
    __shared__ int sdata[256];
    const int b = blockIdx.x, t = threadIdx.x;
    const int base = b * SCAN_CHUNK + t * 4;
    int s = 0;
    #pragma unroll
    for (int i = 0; i < 4; ++i) {
        const int idx = base + i;
        s += (idx < NN) ? cnt[idx] : 0;
    }
    sdata[t] = s;
    __syncthreads();
    for (int off = 128; off > 0; off >>= 1) {
        if (t < off) sdata[t] += sdata[t + off];
        __syncthreads();
    }
    if (t == 0) bsums[b] = sdata[0];
}

// parallel single-block exclusive scan of the 98 block sums (was a serial loop)
__global__ __launch_bounds__(128)
void scan_top_kernel(int* __restrict__ bsums)
{
    __shared__ int s[128];
    const int t = threadIdx.x;
    const int v = (t < SCAN_NB) ? bsums[t] : 0;
    s[t] = v;
    __syncthreads();
    for (int off = 1; off < 128; off <<= 1) {
        const int u = (t >= off) ? s[t - off] : 0;
        __syncthreads();
        s[t] += u;
        __syncthreads();
    }
    if (t < SCAN_NB) bsums[t] = s[t] - v;   // exclusive
}

__global__ __launch_bounds__(256)
void scan_final_kernel(int* __restrict__ cnt, const int* __restrict__ bsums)
{
    __shared__ int sdata[256];
    const int b = blockIdx.x, t = threadIdx.x;
    const int base = b * SCAN_CHUNK + t * 4;
    int c[4];
    #pragma unroll
    for (int i = 0; i < 4; ++i) {
        const int idx = base + i;
        c[i] = (idx < NN) ? cnt[idx] : 0;
    }
    const int tsum = c[0] + c[1] + c[2] + c[3];
    sdata[t] = tsum;
    __syncthreads();
    for (int off = 1; off < 256; off <<= 1) {
        const int v = (t >= off) ? sdata[t - off] : 0;
        __syncthreads();
        sdata[t] += v;
        __syncthreads();
    }
    int off0 = bsums[b] + sdata[t] - tsum;
    #pragma unroll
    for (int i = 0; i < 4; ++i) {
        const int idx = base + i;
        if (idx < NN) cnt[idx] = off0;
        off0 += c[i];
    }
}

__global__ __launch_bounds__(256)
void scatter_kernel(const int* __restrict__ src, const int* __restrict__ dst,
                    int* __restrict__ starts,
                    int2* __restrict__ ps, int* __restrict__ dsts_s)
{
    for (int e = blockIdx.x * blockDim.x + threadIdx.x; e < NE;
         e += gridDim.x * blockDim.x) {
        const int d = dst[e];
        const int pos = atomicAdd(&starts[d], 1);
        ps[pos] = make_int2(e, src[e]);
        dsts_s[pos] = d;
    }
}

// ===========================================================================
// Sorted edge kernel. Each wave owns a CONTIGUOUS range of 16-edge tiles
// (dst ascending), computes the two MFMAs, then does an exact segmented
// reduction over dst runs:
//   - within-lane chain over its 4 C-rows
//   - cross-q-group merge via shuffles (run structure is wave-uniform)
//   - cross-tile carry per wave
// Flushes ~= 64 * (#runs + #waves) ~= 7M atomics (vs 102M naive).
// mfma_f32_16x16x32_bf16: A/B: idx=lane&15, k=(lane>>4)*8+j ; C/D: col=lane&15,
// row=(lane>>4)*4+reg.
// ===========================================================================
#define EK_BLOCKS 1024
#define EK_WAVES (EK_BLOCKS * 4)

__global__ __launch_bounds__(256)
void edge_kernel_sorted(const float* __restrict__ x,
                        const int2* __restrict__ ps,
                        const int* __restrict__ dsts_s,
                        const float* __restrict__ eattr,
                        const float* __restrict__ We,
                        const float* __restrict__ be,
                        const float* __restrict__ Wm,
                        const float* __restrict__ bm,
                        float* __restrict__ agg)
{
    __shared__ float ltile[4][16 * 68];     // per-wave f32 16x64 tile, stride 68
    const int lane = threadIdx.x & 63;
    const int wid  = threadIdx.x >> 6;
    const int m = lane & 15;
    const int q = lane >> 4;
    float* tile = ltile[wid];

    // register-resident B-fragments of We, Wm
    short8 wef[2][4], wmf[2][4];
    float bev[4], bmv[4];
    #pragma unroll
    for (int kh = 0; kh < 2; ++kh)
        #pragma unroll
        for (int t = 0; t < 4; ++t) {
            BF8 fe, fm;
            #pragma unroll
            for (int j = 0; j < 8; ++j) {
                const int k = kh * 32 + q * 8 + j;
                const int n = m + 16 * t;
                fe.s[j] = f2bf(We[k * 64 + n]);
                fm.s[j] = f2bf(Wm[k * 64 + n]);
            }
            wef[kh][t] = fe.v; wmf[kh][t] = fm.v;
        }
    #pragma unroll
    for (int t = 0; t < 4; ++t) { bev[t] = be[m + 16 * t]; bmv[t] = bm[m + 16 * t]; }

    const int n_tiles = NE / 16;
    const int tpw = (n_tiles + EK_WAVES - 1) / EK_WAVES;
    const int w = blockIdx.x * 4 + wid;
    const int tl0 = w * tpw;
    const int tl1 = min(n_tiles, tl0 + tpw);
    if (tl0 >= tl1) return;

    // preload first tile
    int2 pv = ps[tl0 * 16 + m];                         // {edge_id, src}
    int4 dnv = *(const int4*)&dsts_s[tl0 * 16 + q * 4]; // dsts of my 4 rows
    floatx4 ea[4];
    {
        const float* p = eattr + (size_t)pv.x * 64 + q * 8;
        ea[0] = *(const floatx4*)p;        ea[1] = *(const floatx4*)(p + 4);
        ea[2] = *(const floatx4*)(p + 32); ea[3] = *(const floatx4*)(p + 36);
    }

    float cv[4] = {0.f, 0.f, 0.f, 0.f};   // wave carry (replicated in all lanes)
    int cd = -1;

    for (int tl = tl0; tl < tl1; ++tl) {
        const bool haveNext = (tl + 1 < tl1);
        // ---- prefetch next tile (indices + eattr rows) ----
        int2 pvn = pv; int4 dnn = dnv; floatx4 ean[4];
        if (haveNext) {
            const int e0n = (tl + 1) * 16;
            pvn = ps[e0n + m];
            dnn = *(const int4*)&dsts_s[e0n + q * 4];
            const float* p = eattr + (size_t)pvn.x * 64 + q * 8;
            ean[0] = *(const floatx4*)p;        ean[1] = *(const floatx4*)(p + 4);
            ean[2] = *(const floatx4*)(p + 32); ean[3] = *(const floatx4*)(p + 36);
        }
        // ---- issue x-row loads early (src known at loop top) ----
        floatx4 xv[4];
        {
            const float* xp = x + (size_t)pv.y * 64 + q * 8;
            xv[0] = *(const floatx4*)xp;        xv[1] = *(const floatx4*)(xp + 4);
            xv[2] = *(const floatx4*)(xp + 32); xv[3] = *(const floatx4*)(xp + 36);
        }

        // ---- matmul 1: EA = edge_attr @ We ----
        short8 a1[2];
        {
            F4 u0, u1, u2, u3;
            u0.v = ea[0]; u1.v = ea[1]; u2.v = ea[2]; u3.v = ea[3];
            BF8 f0, f1;
            #pragma unroll
            for (int j = 0; j < 4; ++j) {
                f0.s[j] = f2bf(u0.f[j]); f0.s[j + 4] = f2bf(u1.f[j]);
                f1.s[j] = f2bf(u2.f[j]); f1.s[j + 4] = f2bf(u3.f[j]);
            }
            a1[0] = f0.v; a1[1] = f1.v;
        }
        floatx4 acc[4];
        #pragma unroll
        for (int t = 0; t < 4; ++t) acc[t] = (floatx4){0.f, 0.f, 0.f, 0.f};
        #pragma unroll
        for (int kh = 0; kh < 2; ++kh)
            #pragma unroll
            for (int t = 0; t < 4; ++t)
                acc[t] = __builtin_amdgcn_mfma_f32_16x16x32_bf16(a1[kh], wef[kh][t], acc[t], 0, 0, 0);

        // silu+bias -> LDS (f32, C-layout -> row-major)
        #pragma unroll
        for (int t = 0; t < 4; ++t)
            #pragma unroll
            for (int r = 0; r < 4; ++r)
                tile[(q * 4 + r) * 68 + m + 16 * t] = silu_f(acc[t][r] + bev[t]);
        __asm__ volatile("s_waitcnt lgkmcnt(0)" ::: "memory");  // wave-sync RAW

        // ---- matmul 2: A = relu(x[src] + EA) ----
        short8 a2[2];
        {
            const float* lp = &tile[m * 68 + q * 8];
            floatx4 t0 = *(const floatx4*)lp;        floatx4 t1 = *(const floatx4*)(lp + 4);
            floatx4 t2 = *(const floatx4*)(lp + 32); floatx4 t3 = *(const floatx4*)(lp + 36);
            F4 a, b, c, d, X0, X1, X2, X3;
            a.v = t0; b.v = t1; c.v = t2; d.v = t3;
            X0.v = xv[0]; X1.v = xv[1]; X2.v = xv[2]; X3.v = xv[3];
            BF8 f0, f1;
            #pragma unroll
            for (int j = 0; j < 4; ++j) {
                f0.s[j]     = f2bf(fmaxf(a.f[j] + X0.f[j], 0.0f));
                f0.s[j + 4] = f2bf(fmaxf(b.f[j] + X1.f[j], 0.0f));
                f1.s[j]     = f2bf(fmaxf(c.f[j] + X2.f[j], 0.0f));
                f1.s[j + 4] = f2bf(fmaxf(d.f[j] + X3.f[j], 0.0f));
            }
            a2[0] = f0.v; a2[1] = f1.v;
        }
        #pragma unroll
        for (int t = 0; t < 4; ++t) acc[t] = (floatx4){0.f, 0.f, 0.f, 0.f};
        #pragma unroll
        for (int kh = 0; kh < 2; ++kh)
            #pragma unroll
            for (int t = 0; t < 4; ++t)
                acc[t] = __builtin_amdgcn_mfma_f32_16x16x32_bf16(a2[kh], wmf[kh][t], acc[t], 0, 0, 0);

        float sv[4][4];
        #pragma unroll
        for (int t = 0; t < 4; ++t)
            #pragma unroll
            for (int r = 0; r < 4; ++r)
                sv[t][r] = silu_f(acc[t][r] + bmv[t]);

        // ---- segmented flush ----
        const int dn[4] = {dnv.x, dnv.y, dnv.z, dnv.w};
        #define FLUSH(DN, VAL)                                                  \
            do {                                                                \
                atomicAdd(agg + (size_t)(DN) * 64 + m,      (VAL)[0]);          \
                atomicAdd(agg + (size_t)(DN) * 64 + m + 16, (VAL)[1]);          \
                atomicAdd(agg + (size_t)(DN) * 64 + m + 32, (VAL)[2]);          \
                atomicAdd(agg + (size_t)(DN) * 64 + m + 48, (VAL)[3]);          \
            } while (0)

        // within-lane chain over rows q*4 .. q*4+3
        float run[4], head[4] = {0.f, 0.f, 0.f, 0.f};
        const int hd = dn[0];
        int rd = dn[0];
        bool headClosed = false;
        #pragma unroll
        for (int t = 0; t < 4; ++t) run[t] = sv[t][0];
        #pragma unroll
        for (int r = 1; r < 4; ++r) {
            if (dn[r] == rd) {
                #pragma unroll
                for (int t = 0; t < 4; ++t) run[t] += sv[t][r];
            } else {
                if (!headClosed) {
                    #pragma unroll
                    for (int t = 0; t < 4; ++t) head[t] = run[t];
                    headClosed = true;
                } else {
                    FLUSH(rd, run);              // interior run
                }
                #pragma unroll
                for (int t = 0; t < 4; ++t) run[t] = sv[t][r];
                rd = dn[r];
            }
        }
        const bool pure = !headClosed;           // whole 4-row group is one run
        float tail[4]; const int td = rd;
        #pragma unroll
        for (int t = 0; t < 4; ++t) tail[t] = run[t];

        // cross-q-group merge, sequential g=0..3 (run structure wave-uniform)
        float tl_[4]; int td_;                   // mutable tail (carry source)
        #pragma unroll
        for (int t = 0; t < 4; ++t) tl_[t] = tail[t];
        td_ = td;
        #pragma unroll
        for (int g = 0; g < 4; ++g) {
            float iv[4]; int ivd;
            if (g == 0) {
                #pragma unroll
                for (int t = 0; t < 4; ++t) iv[t] = cv[t];
                ivd = cd;
            } else {
                const int sl = m + (g - 1) * 16;
                #pragma unroll
                for (int t = 0; t < 4; ++t) iv[t] = __shfl(tl_[t], sl, 64);
                ivd = __shfl(td_, (g - 1) * 16, 64);
            }
            const int hdg = __shfl(hd, g * 16, 64);
            const bool mine = (q == g);
            if (ivd == hdg) {
                if (mine) {
                    if (pure) {
                        #pragma unroll
                        for (int t = 0; t < 4; ++t) tl_[t] += iv[t];
                    } else {
                        #pragma unroll
                        for (int t = 0; t < 4; ++t) head[t] += iv[t];
                    }
                }
            } else {
                if (g == 0) {
                    if (q == 0 && cd >= 0) FLUSH(cd, iv);
                } else {
                    if (q == g - 1) FLUSH(td_, tl_);
                }
            }
            if (mine && !pure) FLUSH(hd, head);
        }
        // new carry = tail of group 3
        #pragma unroll
        for (int t = 0; t < 4; ++t) cv[t] = __shfl(tl_[t], m + 48, 64);
        cd = __shfl(td_, 48, 64);

        // rotate prefetched state
        pv = pvn; dnv = dnn;
        #pragma unroll
        for (int t = 0; t < 4; ++t) ea[t] = ean[t];
    }
    // final carry flush
    if (q == 0 && cd >= 0) {
        atomicAdd(agg + (size_t)cd * 64 + m,      cv[0]);
        atomicAdd(agg + (size_t)cd * 64 + m + 16, cv[1]);
        atomicAdd(agg + (size_t)cd * 64 + m + 32, cv[2]);
        atomicAdd(agg + (size_t)cd * 64 + m + 48, cv[3]);
    }
    #undef FLUSH
}

// ===========================================================================
// Fallback (ws too small): unsorted, plain atomics (round-1 structure).
// ===========================================================================
__global__ __launch_bounds__(256)
void edge_kernel_unsorted(const float* __restrict__ x,
                          const int* __restrict__ src,
                          const int* __restrict__ dst,
                          const float* __restrict__ eattr,
                          const float* __restrict__ We,
                          const float* __restrict__ be,
                          const float* __restrict__ Wm,
                          const float* __restrict__ bm,
                          float* __restrict__ agg)
{
    __shared__ float ltile[4][16 * 68];
    const int lane = threadIdx.x & 63;
    const int wid  = threadIdx.x >> 6;
    const int m = lane & 15;
    const int q = lane >> 4;
    float* tile = ltile[wid];

    short8 wef[2][4], wmf[2][4];
    float bev[4], bmv[4];
    #pragma unroll
    for (int kh = 0; kh < 2; ++kh)
        #pragma unroll
        for (int t = 0; t < 4; ++t) {
            BF8 fe, fm;
            #pragma unroll
            for (int j = 0; j < 8; ++j) {
                const int k = kh * 32 + q * 8 + j;
                const int n = m + 16 * t;
                fe.s[j] = f2bf(We[k * 64 + n]);
                fm.s[j] = f2bf(Wm[k * 64 + n]);
            }
            wef[kh][t] = fe.v; wmf[kh][t] = fm.v;
        }
    #pragma unroll
    for (int t = 0; t < 4; ++t) { bev[t] = be[m + 16 * t]; bmv[t] = bm[m + 16 * t]; }

    const int n_tiles = NE / 16;
    const int stride = gridDim.x * 4;
    for (int tl = blockIdx.x * 4 + wid; tl < n_tiles; tl += stride) {
        const int e0 = tl * 16;
        short8 a1[2];
        #pragma unroll
        for (int kh = 0; kh < 2; ++kh) {
            const float* p = eattr + (size_t)(e0 + m) * 64 + kh * 32 + q * 8;
            F4 v0, v1; v0.v = *(const floatx4*)p; v1.v = *(const floatx4*)(p + 4);
            BF8 f;
            #pragma unroll
            for (int j = 0; j < 4; ++j) { f.s[j] = f2bf(v0.f[j]); f.s[j + 4] = f2bf(v1.f[j]); }
            a1[kh] = f.v;
        }
        floatx4 acc[4];
        #pragma unroll
        for (int t = 0; t < 4; ++t) acc[t] = (floatx4){0.f, 0.f, 0.f, 0.f};
        #pragma unroll
        for (int kh = 0; kh < 2; ++kh)
            #pragma unroll
            for (int t = 0; t < 4; ++t)
                acc[t] = __builtin_amdgcn_mfma_f32_16x16x32_bf16(a1[kh], wef[kh][t], acc[t], 0, 0, 0);
        #pragma unroll
        for (int t = 0; t < 4; ++t)
            #pragma unroll
            for (int r = 0; r < 4; ++r)
                tile[(q * 4 + r) * 68 + m + 16 * t] = silu_f(acc[t][r] + bev[t]);
        __asm__ volatile("s_waitcnt lgkmcnt(0)" ::: "memory");
        const int sn = src[e0 + m];
        short8 a2[2];
        {
            const float* lp = &tile[m * 68 + q * 8];
            const float* xp = x + (size_t)sn * 64 + q * 8;
            F4 a, b, c, d, X0, X1, X2, X3;
            a.v = *(const floatx4*)lp;        b.v = *(const floatx4*)(lp + 4);
            c.v = *(const floatx4*)(lp + 32); d.v = *(const floatx4*)(lp + 36);
            X0.v = *(const floatx4*)xp;        X1.v = *(const floatx4*)(xp + 4);
            X2.v = *(const floatx4*)(xp + 32); X3.v = *(const floatx4*)(xp + 36);
            BF8 f0, f1;
            #pragma unroll
            for (int j = 0; j < 4; ++j) {
                f0.s[j]     = f2bf(fmaxf(a.f[j] + X0.f[j], 0.0f));
                f0.s[j + 4] = f2bf(fmaxf(b.f[j] + X1.f[j], 0.0f));
                f1.s[j]     = f2bf(fmaxf(c.f[j] + X2.f[j], 0.0f));
                f1.s[j + 4] = f2bf(fmaxf(d.f[j] + X3.f[j], 0.0f));
            }
            a2[0] = f0.v; a2[1] = f1.v;
        }
        #pragma unroll
        for (int t = 0; t < 4; ++t) acc[t] = (floatx4){0.f, 0.f, 0.f, 0.f};
        #pragma unroll
        for (int kh = 0; kh < 2; ++kh)
            #pragma unroll
            for (int t = 0; t < 4; ++t)
                acc[t] = __builtin_amdgcn_mfma_f32_16x16x32_bf16(a2[kh], wmf[kh][t], acc[t], 0, 0, 0);
        int dn[4];
        #pragma unroll
        for (int r = 0; r < 4; ++r) dn[r] = dst[e0 + q * 4 + r];
        #pragma unroll
        for (int t = 0; t < 4; ++t)
            #pragma unroll
            for (int r = 0; r < 4; ++r)
                atomicAdd(agg + (size_t)dn[r] * 64 + m + 16 * t, silu_f(acc[t][r] + bmv[t]));
    }
}

// ===========================================================================
// Stats: per-graph sum/sumsq/count over pre = agg + (1+eps)*x (n2g sorted).
// ===========================================================================
#define STATS_WAVES 4096
__global__ __launch_bounds__(256)
void stats_kernel(const float* __restrict__ agg,
                  const float* __restrict__ x,
                  const int* __restrict__ n2g,
                  const float* __restrict__ eps,
                  float* __restrict__ gsum,
                  float* __restrict__ gss,
                  float* __restrict__ gcnt)
{
    const int lane = threadIdx.x & 63;
    const int wid  = threadIdx.x >> 6;
    const int w    = blockIdx.x * 4 + wid;
    const int chunk = (NN + STATS_WAVES - 1) / STATS_WAVES;
    const int n0 = w * chunk;
    const int n1 = min(NN, n0 + chunk);
    if (n0 >= n1) return;
    const float k = 1.0f + eps[0];

    int   curg = n2g[n0];
    float s = 0.f, ss = 0.f, rc = 0.f;
    for (int n = n0; n < n1; ++n) {
        const int g = n2g[n];
        if (g != curg) {
            float a = s, b = ss;
            #pragma unroll
            for (int off = 32; off > 0; off >>= 1) {
                a += __shfl_down(a, off, 64);
                b += __shfl_down(b, off, 64);
            }
            if (lane == 0) {
                atomicAdd(&gsum[curg], a);
                atomicAdd(&gss[curg], b);
                atomicAdd(&gcnt[curg], rc);
            }
            s = 0.f; ss = 0.f; rc = 0.f; curg = g;
        }
        const float pre = agg[(size_t)n * 64 + lane] + k * x[(size_t)n * 64 + lane];
        s += pre; ss += pre * pre; rc += (lane == 0) ? 1.0f : 0.0f;
    }
    float a = s, b = ss;
    #pragma unroll
    for (int off = 32; off > 0; off >>= 1) {
        a += __shfl_down(a, off, 64);
        b += __shfl_down(b, off, 64);
    }
    if (lane == 0) {
        atomicAdd(&gsum[curg], a);
        atomicAdd(&gss[curg], b);
        atomicAdd(&gcnt[curg], rc);
    }
}

// ===========================================================================
// Norm + residual + relu, in place over agg (== d_out).
// ===========================================================================
__global__ __launch_bounds__(256)
void norm_kernel(const float* __restrict__ x,
                 const int* __restrict__ n2g,
                 const float* __restrict__ eps,
                 const float* __restrict__ gamma,
                 const float* __restrict__ beta,
                 const float* __restrict__ gsum,
                 const float* __restrict__ gss,
                 const float* __restrict__ gcnt,
                 float* __restrict__ out)
{
    const float k = 1.0f + eps[0];
    const int total = NN * 16;
    for (int idx = blockIdx.x * blockDim.x + threadIdx.x; idx < total;
         idx += gridDim.x * blockDim.x) {
        const int n  = idx >> 4;
        const int c4 = (idx & 15) * 4;
        const int g  = n2g[n];
        const float cnt  = fmaxf(gcnt[g] * 64.0f, 1.0f);
        const float mean = gsum[g] / cnt;
        const float var  = gss[g] / cnt - mean * mean;
        const float rsig = rsqrtf(var + LN_EPS);
        F4 a, xv, o;
        a.v  = *(const floatx4*)&out[(size_t)n * 64 + c4];
        xv.v = *(const floatx4*)&x[(size_t)n * 64 + c4];
        #pragma unroll
        for (int j = 0; j < 4; ++j) {
            const float pre = a.f[j] + k * xv.f[j];
            const float v = (pre - mean) * rsig * gamma[c4 + j] + beta[c4 + j] + xv.f[j];
            o.f[j] = fmaxf(v, 0.0f);
        }
        *(floatx4*)&out[(size_t)n * 64 + c4] = o.v;
    }
}

extern "C" void kernel_launch(void* const* d_in, const int* in_sizes, int n_in,
                              void* d_out, int out_size, void* d_ws, size_t ws_size,
                              hipStream_t stream)
{
    const float* x      = (const float*)d_in[0];
    const int*   ei     = (const int*)  d_in[1];
    const float* eattr  = (const float*)d_in[2];
    const int*   n2g    = (const int*)  d_in[3];
    // branch-1 params (d_in[4..10]) are dead: conv1's result is overwritten by
    // conv2(x, ...) in the reference. Only branch 2 affects the output.
    const float* We2    = (const float*)d_in[11];
    const float* be2    = (const float*)d_in[12];
    const float* Wm2    = (const float*)d_in[13];
    const float* bm2    = (const float*)d_in[14];
    const float* eps2   = (const float*)d_in[15];
    const float* gamma2 = (const float*)d_in[16];
    const float* beta2  = (const float*)d_in[17];
    const int* src = ei;
    const int* dst = ei + NE;

    float* out  = (float*)d_out;           // doubles as agg scratch
    // ws: gsum[512] gss[512] gcnt[512] | bsums[128] | cnt[NN] | dsts_s[NE] | ps[2*NE]
    float* gsum = (float*)d_ws;
    float* gss  = gsum + NG;
    float* gcnt = gss + NG;
    int*  bsums  = (int*)(gcnt + NG);
    int*  cnt    = bsums + 128;
    int*  dsts_s = cnt + NN;
    int2* ps     = (int2*)(dsts_s + NE);
    const size_t ws_need = (size_t)(3 * NG + 128 + NN + NE + 2 * (size_t)NE) * 4;
    const bool do_sort = ws_size >= ws_need;

    hipMemsetAsync(d_out, 0, (size_t)NN * 64 * sizeof(float), stream);
    if (do_sort) {
        hipMemsetAsync(d_ws, 0, (size_t)(3 * NG + 128 + NN) * 4, stream);
        hist_kernel<<<dim3(512), dim3(256), 0, stream>>>(dst, cnt);
        scan_partial_kernel<<<dim3(SCAN_NB), dim3(256), 0, stream>>>(cnt, bsums);
        scan_top_kernel<<<dim3(1), dim3(128), 0, stream>>>(bsums);
        scan_final_kernel<<<dim3(SCAN_NB), dim3(256), 0, stream>>>(cnt, bsums);
        scatter_kernel<<<dim3(512), dim3(256), 0, stream>>>(src, dst, cnt, ps, dsts_s);
        edge_kernel_sorted<<<dim3(EK_BLOCKS), dim3(256), 0, stream>>>(
            x, ps, dsts_s, eattr, We2, be2, Wm2, bm2, out);
    } else {
        hipMemsetAsync(d_ws, 0, 3 * NG * sizeof(float), stream);
        edge_kernel_unsorted<<<dim3(2048), dim3(256), 0, stream>>>(
            x, src, dst, eattr, We2, be2, Wm2, bm2, out);
    }
    stats_kernel<<<dim3(STATS_WAVES / 4), dim3(256), 0, stream>>>(
        out, x, n2g, eps2, gsum, gss, gcnt);
    norm_kernel<<<dim3(1024), dim3(256), 0, stream>>>(
        x, n2g, eps2, gamma2, beta2, gsum, gss, gcnt, out);
}

// Round 4
// 883.670 us; speedup vs baseline: 1.2507x; 1.0294x over previous
//
#include <hip/hip_runtime.h>
#include <math.h>

#define NN 100000      // nodes
#define NE 1600000     // edges
#define NG 512         // graphs
#define LN_EPS 1e-5f

typedef __attribute__((ext_vector_type(8))) short short8;
typedef __attribute__((ext_vector_type(4))) float floatx4;

union BF8U { short8 v; unsigned u[4]; };
union F4   { floatx4 v; float f[4]; };

// pack two f32 -> two bf16 in one u32 (round-half-up: 1 add/elem + 1 v_perm/pair)
static __device__ __forceinline__ unsigned pk_bf2(float a, float b) {
    union { float f; unsigned u; } A, B;
    A.f = a; B.f = b;
    const unsigned ua = A.u + 0x8000u;
    const unsigned ub = B.u + 0x8000u;
    return __builtin_amdgcn_perm(ub, ua, 0x07060302u);  // lo16=bf(a), hi16=bf(b)
}
static __device__ __forceinline__ float silu_f(float v) {
    return v * __builtin_amdgcn_rcpf(1.0f + __expf(-v));
}

// ===========================================================================
// x -> bf16 pre-conversion (packed pairs; x_bf row = 32 uints = 128 B)
// ===========================================================================
__global__ __launch_bounds__(256)
void xconv_kernel(const float* __restrict__ x, unsigned* __restrict__ x_bf)
{
    const int total = NN * 32;
    for (int i = blockIdx.x * blockDim.x + threadIdx.x; i < total;
         i += gridDim.x * blockDim.x) {
        const float2 v = *(const float2*)(x + (size_t)i * 2);
        x_bf[i] = pk_bf2(v.x, v.y);
    }
}

// ===========================================================================
// Counting sort of edges by dst. Outputs:
//   ps[pos]    = {edge_id, src}  (int2, coalesced reads in edge kernel)
//   dsts_s[pos]= dst             (sorted ascending)
// ===========================================================================
__global__ __launch_bounds__(256)
void hist_kernel(const int* __restrict__ dst, int* __restrict__ cnt)
{
    for (int e = blockIdx.x * blockDim.x + threadIdx.x; e < NE;
         e += gridDim.x * blockDim.x)
        atomicAdd(&cnt[dst[e]], 1);
}

#define SCAN_CHUNK 1024
#define SCAN_NB ((NN + SCAN_CHUNK - 1) / SCAN_CHUNK)   // 98

__global__ __launch_bounds__(256)
void scan_partial_kernel(const int* __restrict__ cnt, int* __restrict__ bsums)
{
    __shared__ int sdata[256];
    const int b = blockIdx.x, t = threadIdx.x;
    const int base = b * SCAN_CHUNK + t * 4;
    int s = 0;
    #pragma unroll
    for (int i = 0; i < 4; ++i) {
        const int idx = base + i;
        s += (idx < NN) ? cnt[idx] : 0;
    }
    sdata[t] = s;
    __syncthreads();
    for (int off = 128; off > 0; off >>= 1) {
        if (t < off) sdata[t] += sdata[t + off];
        __syncthreads();
    }
    if (t == 0) bsums[b] = sdata[0];
}

__global__ __launch_bounds__(128)
void scan_top_kernel(int* __restrict__ bsums)
{
    __shared__ int s[128];
    const int t = threadIdx.x;
    const int v = (t < SCAN_NB) ? bsums[t] : 0;
    s[t] = v;
    __syncthreads();
    for (int off = 1; off < 128; off <<= 1) {
        const int u = (t >= off) ? s[t - off] : 0;
        __syncthreads();
        s[t] += u;
        __syncthreads();
    }
    if (t < SCAN_NB) bsums[t] = s[t] - v;   // exclusive
}

__global__ __launch_bounds__(256)
void scan_final_kernel(int* __restrict__ cnt, const int* __restrict__ bsums)
{
    __shared__ int sdata[256];
    const int b = blockIdx.x, t = threadIdx.x;
    const int base = b * SCAN_CHUNK + t * 4;
    int c[4];
    #pragma unroll
    for (int i = 0; i < 4; ++i) {
        const int idx = base + i;
        c[i] = (idx < NN) ? cnt[idx] : 0;
    }
    const int tsum = c[0] + c[1] + c[2] + c[3];
    sdata[t] = tsum;
    __syncthreads();
    for (int off = 1; off < 256; off <<= 1) {
        const int v = (t >= off) ? sdata[t - off] : 0;
        __syncthreads();
        sdata[t] += v;
        __syncthreads();
    }
    int off0 = bsums[b] + sdata[t] - tsum;
    #pragma unroll
    for (int i = 0; i < 4; ++i) {
        const int idx = base + i;
        if (idx < NN) cnt[idx] = off0;
        off0 += c[i];
    }
}

__global__ __launch_bounds__(256)
void scatter_kernel(const int* __restrict__ src, const int* __restrict__ dst,
                    int* __restrict__ starts,
                    int2* __restrict__ ps, int* __restrict__ dsts_s)
{
    for (int e = blockIdx.x * blockDim.x + threadIdx.x; e < NE;
         e += gridDim.x * blockDim.x) {
        const int d = dst[e];
        const int pos = atomicAdd(&starts[d], 1);
        ps[pos] = make_int2(e, src[e]);
        dsts_s[pos] = d;
    }
}

// ===========================================================================
// Sorted edge kernel. Wave owns a contiguous run of 16-edge tiles (dst
// ascending): MFMA1 (eattr@We) -> silu -> LDS C->A transform -> add bf16-x,
// relu -> MFMA2 (@Wm) -> silu -> exact segmented reduction over dst runs
// (within-lane chain + cross-q shuffle merge + cross-tile wave carry).
// mfma_f32_16x16x32_bf16: A/B idx=lane&15, k=(lane>>4)*8+j ; C/D col=lane&15,
// row=(lane>>4)*4+reg.
// ===========================================================================
#define EK_BLOCKS 2048
#define EK_WAVES (EK_BLOCKS * 4)

__global__ __launch_bounds__(256)
void edge_kernel_sorted(const unsigned* __restrict__ x_bf,
                        const int2* __restrict__ ps,
                        const int* __restrict__ dsts_s,
                        const float* __restrict__ eattr,
                        const float* __restrict__ We,
                        const float* __restrict__ be,
                        const float* __restrict__ Wm,
                        const float* __restrict__ bm,
                        float* __restrict__ agg)
{
    __shared__ float ltile[4][16 * 68];     // per-wave f32 16x64 tile, stride 68
    const int lane = threadIdx.x & 63;
    const int wid  = threadIdx.x >> 6;
    const int m = lane & 15;
    const int q = lane >> 4;
    float* tile = ltile[wid];

    // register-resident B-fragments of We, Wm
    short8 wef[2][4], wmf[2][4];
    float bev[4], bmv[4];
    #pragma unroll
    for (int kh = 0; kh < 2; ++kh)
        #pragma unroll
        for (int t = 0; t < 4; ++t) {
            BF8U fe, fm;
            #pragma unroll
            for (int p = 0; p < 4; ++p) {
                const int k = kh * 32 + q * 8 + p * 2;
                const int n = m + 16 * t;
                fe.u[p] = pk_bf2(We[k * 64 + n], We[(k + 1) * 64 + n]);
                fm.u[p] = pk_bf2(Wm[k * 64 + n], Wm[(k + 1) * 64 + n]);
            }
            wef[kh][t] = fe.v; wmf[kh][t] = fm.v;
        }
    #pragma unroll
    for (int t = 0; t < 4; ++t) { bev[t] = be[m + 16 * t]; bmv[t] = bm[m + 16 * t]; }

    const int n_tiles = NE / 16;
    const int tpw = (n_tiles + EK_WAVES - 1) / EK_WAVES;
    const int w = blockIdx.x * 4 + wid;
    const int tl0 = w * tpw;
    const int tl1 = min(n_tiles, tl0 + tpw);
    if (tl0 >= tl1) return;

    // preload first tile
    int2 pv = ps[tl0 * 16 + m];                         // {edge_id, src}
    int4 dnv = *(const int4*)&dsts_s[tl0 * 16 + q * 4]; // dsts of my 4 rows
    floatx4 ea[4];
    {
        const float* p = eattr + (size_t)pv.x * 64 + q * 8;
        ea[0] = *(const floatx4*)p;        ea[1] = *(const floatx4*)(p + 4);
        ea[2] = *(const floatx4*)(p + 32); ea[3] = *(const floatx4*)(p + 36);
    }

    float cv[4] = {0.f, 0.f, 0.f, 0.f};   // wave carry (replicated in all lanes)
    int cd = -1;

    for (int tl = tl0; tl < tl1; ++tl) {
        const bool haveNext = (tl + 1 < tl1);
        // ---- prefetch next tile (indices + eattr rows) ----
        int2 pvn = pv; int4 dnn = dnv; floatx4 ean[4];
        if (haveNext) {
            const int e0n = (tl + 1) * 16;
            pvn = ps[e0n + m];
            dnn = *(const int4*)&dsts_s[e0n + q * 4];
            const float* p = eattr + (size_t)pvn.x * 64 + q * 8;
            ean[0] = *(const floatx4*)p;        ean[1] = *(const floatx4*)(p + 4);
            ean[2] = *(const floatx4*)(p + 32); ean[3] = *(const floatx4*)(p + 36);
        }
        // ---- issue x-row loads early (bf16-packed, 2x16B) ----
        const uint4 xa = *(const uint4*)(x_bf + (size_t)pv.y * 32 + q * 4);
        const uint4 xb = *(const uint4*)(x_bf + (size_t)pv.y * 32 + 16 + q * 4);

        // ---- matmul 1: EA = edge_attr @ We ----
        short8 a1[2];
        {
            F4 u0, u1, u2, u3;
            u0.v = ea[0]; u1.v = ea[1]; u2.v = ea[2]; u3.v = ea[3];
            BF8U f0, f1;
            f0.u[0] = pk_bf2(u0.f[0], u0.f[1]);
            f0.u[1] = pk_bf2(u0.f[2], u0.f[3]);
            f0.u[2] = pk_bf2(u1.f[0], u1.f[1]);
            f0.u[3] = pk_bf2(u1.f[2], u1.f[3]);
            f1.u[0] = pk_bf2(u2.f[0], u2.f[1]);
            f1.u[1] = pk_bf2(u2.f[2], u2.f[3]);
            f1.u[2] = pk_bf2(u3.f[0], u3.f[1]);
            f1.u[3] = pk_bf2(u3.f[2], u3.f[3]);
            a1[0] = f0.v; a1[1] = f1.v;
        }
        floatx4 acc[4];
        #pragma unroll
        for (int t = 0; t < 4; ++t) acc[t] = (floatx4){0.f, 0.f, 0.f, 0.f};
        #pragma unroll
        for (int kh = 0; kh < 2; ++kh)
            #pragma unroll
            for (int t = 0; t < 4; ++t)
                acc[t] = __builtin_amdgcn_mfma_f32_16x16x32_bf16(a1[kh], wef[kh][t], acc[t], 0, 0, 0);

        // silu+bias -> LDS (f32, C-layout -> row-major [edge][channel])
        #pragma unroll
        for (int t = 0; t < 4; ++t)
            #pragma unroll
            for (int r = 0; r < 4; ++r)
                tile[(q * 4 + r) * 68 + m + 16 * t] = silu_f(acc[t][r] + bev[t]);
        __asm__ volatile("s_waitcnt lgkmcnt(0)" ::: "memory");  // wave-sync RAW

        // ---- matmul 2: A = relu(x_bf[src] + EA) ----
        short8 a2[2];
        {
            const float* lp = &tile[m * 68 + q * 8];
            F4 A0, A1, B0, B1;
            A0.v = *(const floatx4*)lp;        A1.v = *(const floatx4*)(lp + 4);
            B0.v = *(const floatx4*)(lp + 32); B1.v = *(const floatx4*)(lp + 36);
            const unsigned xu[8] = {xa.x, xa.y, xa.z, xa.w, xb.x, xb.y, xb.z, xb.w};
            float el[16];
            el[0]=A0.f[0]; el[1]=A0.f[1]; el[2]=A0.f[2]; el[3]=A0.f[3];
            el[4]=A1.f[0]; el[5]=A1.f[1]; el[6]=A1.f[2]; el[7]=A1.f[3];
            el[8]=B0.f[0]; el[9]=B0.f[1]; el[10]=B0.f[2]; el[11]=B0.f[3];
            el[12]=B1.f[0]; el[13]=B1.f[1]; el[14]=B1.f[2]; el[15]=B1.f[3];
            BF8U f0, f1;
            #pragma unroll
            for (int p = 0; p < 8; ++p) {
                union { unsigned u; float f; } lo, hi;
                lo.u = xu[p] << 16; hi.u = xu[p] & 0xffff0000u;
                const float t0 = fmaxf(lo.f + el[p * 2],     0.0f);
                const float t1 = fmaxf(hi.f + el[p * 2 + 1], 0.0f);
                const unsigned pk = pk_bf2(t0, t1);
                if (p < 4) f0.u[p] = pk; else f1.u[p - 4] = pk;
            }
            a2[0] = f0.v; a2[1] = f1.v;
        }
        #pragma unroll
        for (int t = 0; t < 4; ++t) acc[t] = (floatx4){0.f, 0.f, 0.f, 0.f};
        #pragma unroll
        for (int kh = 0; kh < 2; ++kh)
            #pragma unroll
            for (int t = 0; t < 4; ++t)
                acc[t] = __builtin_amdgcn_mfma_f32_16x16x32_bf16(a2[kh], wmf[kh][t], acc[t], 0, 0, 0);

        float sv[4][4];
        #pragma unroll
        for (int t = 0; t < 4; ++t)
            #pragma unroll
            for (int r = 0; r < 4; ++r)
                sv[t][r] = silu_f(acc[t][r] + bmv[t]);

        // ---- segmented flush ----
        const int dn[4] = {dnv.x, dnv.y, dnv.z, dnv.w};
        #define FLUSH(DN, VAL)                                                  \
            do {                                                                \
                atomicAdd(agg + (size_t)(DN) * 64 + m,      (VAL)[0]);          \
                atomicAdd(agg + (size_t)(DN) * 64 + m + 16, (VAL)[1]);          \
                atomicAdd(agg + (size_t)(DN) * 64 + m + 32, (VAL)[2]);          \
                atomicAdd(agg + (size_t)(DN) * 64 + m + 48, (VAL)[3]);          \
            } while (0)

        // within-lane chain over rows q*4 .. q*4+3
        float run[4], head[4] = {0.f, 0.f, 0.f, 0.f};
        const int hd = dn[0];
        int rd = dn[0];
        bool headClosed = false;
        #pragma unroll
        for (int t = 0; t < 4; ++t) run[t] = sv[t][0];
        #pragma unroll
        for (int r = 1; r < 4; ++r) {
            if (dn[r] == rd) {
                #pragma unroll
                for (int t = 0; t < 4; ++t) run[t] += sv[t][r];
            } else {
                if (!headClosed) {
                    #pragma unroll
                    for (int t = 0; t < 4; ++t) head[t] = run[t];
                    headClosed = true;
                } else {
                    FLUSH(rd, run);              // interior run
                }
                #pragma unroll
                for (int t = 0; t < 4; ++t) run[t] = sv[t][r];
                rd = dn[r];
            }
        }
        const bool pure = !headClosed;           // whole 4-row group is one run
        float tail[4]; const int td = rd;
        #pragma unroll
        for (int t = 0; t < 4; ++t) tail[t] = run[t];

        // cross-q-group merge, sequential g=0..3 (run structure wave-uniform)
        float tl_[4]; int td_;
        #pragma unroll
        for (int t = 0; t < 4; ++t) tl_[t] = tail[t];
        td_ = td;
        #pragma unroll
        for (int g = 0; g < 4; ++g) {
            float iv[4]; int ivd;
            if (g == 0) {
                #pragma unroll
                for (int t = 0; t < 4; ++t) iv[t] = cv[t];
                ivd = cd;
            } else {
                const int sl = m + (g - 1) * 16;
                #pragma unroll
                for (int t = 0; t < 4; ++t) iv[t] = __shfl(tl_[t], sl, 64);
                ivd = __shfl(td_, (g - 1) * 16, 64);
            }
            const int hdg = __shfl(hd, g * 16, 64);
            const bool mine = (q == g);
            if (ivd == hdg) {
                if (mine) {
                    if (pure) {
                        #pragma unroll
                        for (int t = 0; t < 4; ++t) tl_[t] += iv[t];
                    } else {
                        #pragma unroll
                        for (int t = 0; t < 4; ++t) head[t] += iv[t];
                    }
                }
            } else {
                if (g == 0) {
                    if (q == 0 && cd >= 0) FLUSH(cd, iv);
                } else {
                    if (q == g - 1) FLUSH(td_, tl_);
                }
            }
            if (mine && !pure) FLUSH(hd, head);
        }
        // new carry = tail of group 3
        #pragma unroll
        for (int t = 0; t < 4; ++t) cv[t] = __shfl(tl_[t], m + 48, 64);
        cd = __shfl(td_, 48, 64);

        // rotate prefetched state
        pv = pvn; dnv = dnn;
        #pragma unroll
        for (int t = 0; t < 4; ++t) ea[t] = ean[t];
    }
    // final carry flush
    if (q == 0 && cd >= 0) {
        atomicAdd(agg + (size_t)cd * 64 + m,      cv[0]);
        atomicAdd(agg + (size_t)cd * 64 + m + 16, cv[1]);
        atomicAdd(agg + (size_t)cd * 64 + m + 32, cv[2]);
        atomicAdd(agg + (size_t)cd * 64 + m + 48, cv[3]);
    }
    #undef FLUSH
}

// ===========================================================================
// Fallback (ws too small): unsorted, plain atomics.
// ===========================================================================
__global__ __launch_bounds__(256)
void edge_kernel_unsorted(const float* __restrict__ x,
                          const int* __restrict__ src,
                          const int* __restrict__ dst,
                          const float* __restrict__ eattr,
                          const float* __restrict__ We,
                          const float* __restrict__ be,
                          const float* __restrict__ Wm,
                          const float* __restrict__ bm,
                          float* __restrict__ agg)
{
    __shared__ float ltile[4][16 * 68];
    const int lane = threadIdx.x & 63;
    const int wid  = threadIdx.x >> 6;
    const int m = lane & 15;
    const int q = lane >> 4;
    float* tile = ltile[wid];

    short8 wef[2][4], wmf[2][4];
    float bev[4], bmv[4];
    #pragma unroll
    for (int kh = 0; kh < 2; ++kh)
        #pragma unroll
        for (int t = 0; t < 4; ++t) {
            BF8U fe, fm;
            #pragma unroll
            for (int p = 0; p < 4; ++p) {
                const int k = kh * 32 + q * 8 + p * 2;
                const int n = m + 16 * t;
                fe.u[p] = pk_bf2(We[k * 64 + n], We[(k + 1) * 64 + n]);
                fm.u[p] = pk_bf2(Wm[k * 64 + n], Wm[(k + 1) * 64 + n]);
            }
            wef[kh][t] = fe.v; wmf[kh][t] = fm.v;
        }
    #pragma unroll
    for (int t = 0; t < 4; ++t) { bev[t] = be[m + 16 * t]; bmv[t] = bm[m + 16 * t]; }

    const int n_tiles = NE / 16;
    const int stride = gridDim.x * 4;
    for (int tl = blockIdx.x * 4 + wid; tl < n_tiles; tl += stride) {
        const int e0 = tl * 16;
        short8 a1[2];
        #pragma unroll
        for (int kh = 0; kh < 2; ++kh) {
            const float* p = eattr + (size_t)(e0 + m) * 64 + kh * 32 + q * 8;
            F4 v0, v1; v0.v = *(const floatx4*)p; v1.v = *(const floatx4*)(p + 4);
            BF8U f;
            f.u[0] = pk_bf2(v0.f[0], v0.f[1]);
            f.u[1] = pk_bf2(v0.f[2], v0.f[3]);
            f.u[2] = pk_bf2(v1.f[0], v1.f[1]);
            f.u[3] = pk_bf2(v1.f[2], v1.f[3]);
            a1[kh] = f.v;
        }
        floatx4 acc[4];
        #pragma unroll
        for (int t = 0; t < 4; ++t) acc[t] = (floatx4){0.f, 0.f, 0.f, 0.f};
        #pragma unroll
        for (int kh = 0; kh < 2; ++kh)
            #pragma unroll
            for (int t = 0; t < 4; ++t)
                acc[t] = __builtin_amdgcn_mfma_f32_16x16x32_bf16(a1[kh], wef[kh][t], acc[t], 0, 0, 0);
        #pragma unroll
        for (int t = 0; t < 4; ++t)
            #pragma unroll
            for (int r = 0; r < 4; ++r)
                tile[(q * 4 + r) * 68 + m + 16 * t] = silu_f(acc[t][r] + bev[t]);
        __asm__ volatile("s_waitcnt lgkmcnt(0)" ::: "memory");
        const int sn = src[e0 + m];
        short8 a2[2];
        {
            const float* lp = &tile[m * 68 + q * 8];
            const float* xp = x + (size_t)sn * 64 + q * 8;
            F4 a, b, c, d, X0, X1, X2, X3;
            a.v = *(const floatx4*)lp;        b.v = *(const floatx4*)(lp + 4);
            c.v = *(const floatx4*)(lp + 32); d.v = *(const floatx4*)(lp + 36);
            X0.v = *(const floatx4*)xp;        X1.v = *(const floatx4*)(xp + 4);
            X2.v = *(const floatx4*)(xp + 32); X3.v = *(const floatx4*)(xp + 36);
            BF8U f0, f1;
            f0.u[0] = pk_bf2(fmaxf(a.f[0]+X0.f[0],0.f), fmaxf(a.f[1]+X0.f[1],0.f));
            f0.u[1] = pk_bf2(fmaxf(a.f[2]+X0.f[2],0.f), fmaxf(a.f[3]+X0.f[3],0.f));
            f0.u[2] = pk_bf2(fmaxf(b.f[0]+X1.f[0],0.f), fmaxf(b.f[1]+X1.f[1],0.f));
            f0.u[3] = pk_bf2(fmaxf(b.f[2]+X1.f[2],0.f), fmaxf(b.f[3]+X1.f[3],0.f));
            f1.u[0] = pk_bf2(fmaxf(c.f[0]+X2.f[0],0.f), fmaxf(c.f[1]+X2.f[1],0.f));
            f1.u[1] = pk_bf2(fmaxf(c.f[2]+X2.f[2],0.f), fmaxf(c.f[3]+X2.f[3],0.f));
            f1.u[2] = pk_bf2(fmaxf(d.f[0]+X3.f[0],0.f), fmaxf(d.f[1]+X3.f[1],0.f));
            f1.u[3] = pk_bf2(fmaxf(d.f[2]+X3.f[2],0.f), fmaxf(d.f[3]+X3.f[3],0.f));
            a2[0] = f0.v; a2[1] = f1.v;
        }
        #pragma unroll
        for (int t = 0; t < 4; ++t) acc[t] = (floatx4){0.f, 0.f, 0.f, 0.f};
        #pragma unroll
        for (int kh = 0; kh < 2; ++kh)
            #pragma unroll
            for (int t = 0; t < 4; ++t)
                acc[t] = __builtin_amdgcn_mfma_f32_16x16x32_bf16(a2[kh], wmf[kh][t], acc[t], 0, 0, 0);
        int dn[4];
        #pragma unroll
        for (int r = 0; r < 4; ++r) dn[r] = dst[e0 + q * 4 + r];
        #pragma unroll
        for (int t = 0; t < 4; ++t)
            #pragma unroll
            for (int r = 0; r < 4; ++r)
                atomicAdd(agg + (size_t)dn[r] * 64 + m + 16 * t, silu_f(acc[t][r] + bmv[t]));
    }
}

// ===========================================================================
// Stats: per-graph sum/sumsq/count over pre = agg + (1+eps)*x (n2g sorted).
// ===========================================================================
#define STATS_WAVES 4096
__global__ __launch_bounds__(256)
void stats_kernel(const float* __restrict__ agg,
                  const float* __restrict__ x,
                  const int* __restrict__ n2g,
                  const float* __restrict__ eps,
                  float* __restrict__ gsum,
                  float* __restrict__ gss,
                  float* __restrict__ gcnt)
{
    const int lane = threadIdx.x & 63;
    const int wid  = threadIdx.x >> 6;
    const int w    = blockIdx.x * 4 + wid;
    const int chunk = (NN + STATS_WAVES - 1) / STATS_WAVES;
    const int n0 = w * chunk;
    const int n1 = min(NN, n0 + chunk);
    if (n0 >= n1) return;
    const float k = 1.0f + eps[0];

    int   curg = n2g[n0];
    float s = 0.f, ss = 0.f, rc = 0.f;
    for (int n = n0; n < n1; ++n) {
        const int g = n2g[n];
        if (g != curg) {
            float a = s, b = ss;
            #pragma unroll
            for (int off = 32; off > 0; off >>= 1) {
                a += __shfl_down(a, off, 64);
                b += __shfl_down(b, off, 64);
            }
            if (lane == 0) {
                atomicAdd(&gsum[curg], a);
                atomicAdd(&gss[curg], b);
                atomicAdd(&gcnt[curg], rc);
            }
            s = 0.f; ss = 0.f; rc = 0.f; curg = g;
        }
        const float pre = agg[(size_t)n * 64 + lane] + k * x[(size_t)n * 64 + lane];
        s += pre; ss += pre * pre; rc += (lane == 0) ? 1.0f : 0.0f;
    }
    float a = s, b = ss;
    #pragma unroll
    for (int off = 32; off > 0; off >>= 1) {
        a += __shfl_down(a, off, 64);
        b += __shfl_down(b, off, 64);
    }
    if (lane == 0) {
        atomicAdd(&gsum[curg], a);
        atomicAdd(&gss[curg], b);
        atomicAdd(&gcnt[curg], rc);
    }
}

// ===========================================================================
// Norm + residual + relu, in place over agg (== d_out).
// ===========================================================================
__global__ __launch_bounds__(256)
void norm_kernel(const float* __restrict__ x,
                 const int* __restrict__ n2g,
                 const float* __restrict__ eps,
                 const float* __restrict__ gamma,
                 const float* __restrict__ beta,
                 const float* __restrict__ gsum,
                 const float* __restrict__ gss,
                 const float* __restrict__ gcnt,
                 float* __restrict__ out)
{
    const float k = 1.0f + eps[0];
    const int total = NN * 16;
    for (int idx = blockIdx.x * blockDim.x + threadIdx.x; idx < total;
         idx += gridDim.x * blockDim.x) {
        const int n  = idx >> 4;
        const int c4 = (idx & 15) * 4;
        const int g  = n2g[n];
        const float cnt  = fmaxf(gcnt[g] * 64.0f, 1.0f);
        const float mean = gsum[g] / cnt;
        const float var  = gss[g] / cnt - mean * mean;
        const float rsig = rsqrtf(var + LN_EPS);
        F4 a, xv, o;
        a.v  = *(const floatx4*)&out[(size_t)n * 64 + c4];
        xv.v = *(const floatx4*)&x[(size_t)n * 64 + c4];
        #pragma unroll
        for (int j = 0; j < 4; ++j) {
            const float pre = a.f[j] + k * xv.f[j];
            const float v = (pre - mean) * rsig * gamma[c4 + j] + beta[c4 + j] + xv.f[j];
            o.f[j] = fmaxf(v, 0.0f);
        }
        *(floatx4*)&out[(size_t)n * 64 + c4] = o.v;
    }
}

extern "C" void kernel_launch(void* const* d_in, const int* in_sizes, int n_in,
                              void* d_out, int out_size, void* d_ws, size_t ws_size,
                              hipStream_t stream)
{
    const float* x      = (const float*)d_in[0];
    const int*   ei     = (const int*)  d_in[1];
    const float* eattr  = (const float*)d_in[2];
    const int*   n2g    = (const int*)  d_in[3];
    // branch-1 params (d_in[4..10]) are dead: conv1's result is overwritten by
    // conv2(x, ...) in the reference. Only branch 2 affects the output.
    const float* We2    = (const float*)d_in[11];
    const float* be2    = (const float*)d_in[12];
    const float* Wm2    = (const float*)d_in[13];
    const float* bm2    = (const float*)d_in[14];
    const float* eps2   = (const float*)d_in[15];
    const float* gamma2 = (const float*)d_in[16];
    const float* beta2  = (const float*)d_in[17];
    const int* src = ei;
    const int* dst = ei + NE;

    float* out  = (float*)d_out;           // doubles as agg scratch
    // ws: gsum[512] gss[512] gcnt[512] | bsums[128] | cnt[NN] | dsts_s[NE]
    //     | ps[2*NE] | x_bf[NN*32]
    float* gsum = (float*)d_ws;
    float* gss  = gsum + NG;
    float* gcnt = gss + NG;
    int*  bsums  = (int*)(gcnt + NG);
    int*  cnt    = bsums + 128;
    int*  dsts_s = cnt + NN;
    int2* ps     = (int2*)(dsts_s + NE);
    unsigned* x_bf = (unsigned*)(ps + NE);
    const size_t ws_need = (size_t)(3 * NG + 128 + NN + NE + 2 * (size_t)NE
                                    + (size_t)NN * 32) * 4;
    const bool do_sort = ws_size >= ws_need;

    hipMemsetAsync(d_out, 0, (size_t)NN * 64 * sizeof(float), stream);
    if (do_sort) {
        hipMemsetAsync(d_ws, 0, (size_t)(3 * NG + 128 + NN) * 4, stream);
        xconv_kernel<<<dim3(512), dim3(256), 0, stream>>>(x, x_bf);
        hist_kernel<<<dim3(512), dim3(256), 0, stream>>>(dst, cnt);
        scan_partial_kernel<<<dim3(SCAN_NB), dim3(256), 0, stream>>>(cnt, bsums);
        scan_top_kernel<<<dim3(1), dim3(128), 0, stream>>>(bsums);
        scan_final_kernel<<<dim3(SCAN_NB), dim3(256), 0, stream>>>(cnt, bsums);
        scatter_kernel<<<dim3(512), dim3(256), 0, stream>>>(src, dst, cnt, ps, dsts_s);
        edge_kernel_sorted<<<dim3(EK_BLOCKS), dim3(256), 0, stream>>>(
            x_bf, ps, dsts_s, eattr, We2, be2, Wm2, bm2, out);
    } else {
        hipMemsetAsync(d_ws, 0, 3 * NG * sizeof(float), stream);
        edge_kernel_unsorted<<<dim3(2048), dim3(256), 0, stream>>>(
            x, src, dst, eattr, We2, be2, Wm2, bm2, out);
    }
    stats_kernel<<<dim3(STATS_WAVES / 4), dim3(256), 0, stream>>>(
        out, x, n2g, eps2, gsum, gss, gcnt);
    norm_kernel<<<dim3(1024), dim3(256), 0, stream>>>(
        x, n2g, eps2, gamma2, beta2, gsum, gss, gcnt, out);
}